// Round 21
// baseline (24.144 us; speedup 1.0000x reference)
//
#include <hip/hip_runtime.h>
#include <math.h>

#define B_ 128
#define N_ 16800
#define N4_ 4200             // uint4 units per row
#define NTAIL (N4_ - 4096)   // 104 tail uint4 units
#define NTHR 1024
#define NBINS 1024           // linear bins over x in [-8,8), width 1/64
#define HPAD32 1032          // padded sub-hist stride (u32)
#define NSUB 4
#define XSCALE 64.0f
#define XOFF 512.0f
#define INV_XSCALE (1.0f / 64.0f)
#define FLT_EPS_ 1.1920929e-7f

typedef unsigned int u32;

// numerically stable softplus: log(1+e^t) = max(t,0) + log1p(e^{-|t|})
__device__ __forceinline__ float softplus_of(float t) {
    return fmaxf(t, 0.f) + __logf(1.f + __expf(-fabsf(t)));
}
// x-space bin: monotone in x, hence monotone in lneg = softplus(x)
__device__ __forceinline__ u32 xbin_of(float x) {
    float fb = fmaf(x, XSCALE, XOFF);
    int ib = (int)fb;
    ib = (ib < 0) ? 0 : ((ib > NBINS - 1) ? NBINS - 1 : ib);
    return (u32)ib;
}
// value of a bin = softplus at its x-center
__device__ __forceinline__ float binval_of(u32 bin) {
    float cx = ((float)bin + 0.5f) * INV_XSCALE - 8.0f;
    return softplus_of(cx);
}

// R20 row_kernel, byte-identical. MEASUREMENT: launched twice in this round.
__global__ __launch_bounds__(NTHR) void row_kernel(
    const float* __restrict__ pbboxs,
    const float* __restrict__ plabels,
    const float* __restrict__ gbboxs,
    const float* __restrict__ glabels,
    const float* __restrict__ ancs,
    float* __restrict__ g_rowc)   // [3][B_]
{
    __shared__ u32   s_hc[NSUB * HPAD32];   // 16.5 KB
    __shared__ int   s_posn[N_];            // 67.2 KB
    __shared__ float s_posv[N_];            // 67.2 KB
    __shared__ u32   s_pcnt;
    __shared__ float s_rf[16], s_rf2[16];
    __shared__ float s_sg[16];
    __shared__ u32   s_wt[16];
    __shared__ u32   s_sel[2];

    const int tid  = threadIdx.x;
    const int lane = tid & 63;
    const int wave = tid >> 6;
    const int b    = blockIdx.x;

    for (int j = tid; j < NSUB * HPAD32; j += NTHR) s_hc[j] = 0u;
    if (tid == 0) s_pcnt = 0u;
    __syncthreads();

    const uint4* pl4 = (const uint4*)(plabels + (size_t)b * N_);
    const uint4* gl4 = (const uint4*)(glabels + (size_t)b * N_);

    u32* myh = s_hc + (wave & (NSUB - 1)) * HPAD32;

    // ---- dense phase: ALL loads issued in one burst; no transcendentals ----
    {
        const bool has_tail = (tid < NTAIL);
        uint4 xu[4], yu[4], xt, yt;
        #pragma unroll
        for (int k = 0; k < 4; ++k) {
            xu[k] = pl4[tid + 1024 * k];
            yu[k] = gl4[tid + 1024 * k];
        }
        if (has_tail) { xt = pl4[4096 + tid]; yt = gl4[4096 + tid]; }

        #pragma unroll
        for (int k = 0; k < 4; ++k) {
            u32 xb[4] = {xu[k].x, xu[k].y, xu[k].z, xu[k].w};
            u32 yb[4] = {yu[k].x, yu[k].y, yu[k].z, yu[k].w};
            #pragma unroll
            for (int j = 0; j < 4; ++j) {
                float x = __uint_as_float(xb[j]);
                float y = __uint_as_float(yb[j]);
                bool pos = (y > 0.f);
                u32 bin = pos ? 0u : xbin_of(x);
                atomicAdd(&myh[bin], 1u);
                if (pos) {
                    u32 idx = atomicAdd(&s_pcnt, 1u);
                    s_posn[idx] = (tid + 1024 * k) * 4 + j;
                    s_posv[idx] = x;
                }
            }
        }
        if (has_tail) {
            u32 xb[4] = {xt.x, xt.y, xt.z, xt.w};
            u32 yb[4] = {yt.x, yt.y, yt.z, yt.w};
            #pragma unroll
            for (int j = 0; j < 4; ++j) {
                float x = __uint_as_float(xb[j]);
                float y = __uint_as_float(yb[j]);
                bool pos = (y > 0.f);
                u32 bin = pos ? 0u : xbin_of(x);
                atomicAdd(&myh[bin], 1u);
                if (pos) {
                    u32 idx = atomicAdd(&s_pcnt, 1u);
                    s_posn[idx] = (4096 + tid) * 4 + j;
                    s_posv[idx] = x;
                }
            }
        }
    }
    __syncthreads();

    // ---- positive phase: one scattered burst; bce = softplus(-x) ----
    const int pcnt = (int)s_pcnt;
    const float4* p4 = (const float4*)(pbboxs + (size_t)b * N_ * 4);
    const float4* g4 = (const float4*)(gbboxs + (size_t)b * N_ * 4);
    const float4* a4 = (const float4*)ancs;

    float acc_lb = 0.f, acc_pb = 0.f;
    for (int i = tid; i < pcnt; i += NTHR) {
        int n = s_posn[i];
        acc_pb += softplus_of(-s_posv[i]);
        float4 p = p4[n], g = g4[n], a = a4[n];
        float d0 = p.x - 10.f * __fdividef(g.x - a.x, a.z);
        float d1 = p.y - 10.f * __fdividef(g.y - a.y, a.w);
        float d2 = p.z - 5.f * __logf(__fdividef(g.z, a.z));
        float d3 = p.w - 5.f * __logf(__fdividef(g.w, a.w));
        float a0 = fabsf(d0), a1 = fabsf(d1), a2 = fabsf(d2), a3 = fabsf(d3);
        acc_lb += ((a0 < 1.f) ? 0.5f * d0 * d0 : a0 - 0.5f)
                + ((a1 < 1.f) ? 0.5f * d1 * d1 : a1 - 0.5f)
                + ((a2 < 1.f) ? 0.5f * d2 * d2 : a2 - 0.5f)
                + ((a3 < 1.f) ? 0.5f * d3 * d3 : a3 - 0.5f);
    }
    #pragma unroll
    for (int off = 32; off > 0; off >>= 1) {
        acc_lb += __shfl_xor(acc_lb, off);
        acc_pb += __shfl_xor(acc_pb, off);
    }
    if (lane == 0) { s_rf[wave] = acc_lb; s_rf2[wave] = acc_pb; }
    __syncthreads();

    // ---- in-block select: 1024 bins, one per thread ----
    const int k = (3 * pcnt > N_) ? N_ : 3 * pcnt;
    float sum_sel = 0.f;
    if (k > 0) {
        u32 c = s_hc[tid] + s_hc[HPAD32 + tid] + s_hc[2 * HPAD32 + tid] + s_hc[3 * HPAD32 + tid];
        u32 suf = c;
        #pragma unroll
        for (int off = 1; off < 64; off <<= 1) {
            u32 o = __shfl_down(suf, off);
            if (lane + off < 64) suf += o;
        }
        if (lane == 0) s_wt[wave] = suf;
        __syncthreads();
        u32 above = 0u;
        for (int w = wave + 1; w < 16; ++w) above += s_wt[w];
        u32 r  = suf + above;
        u32 r2 = r - c;
        if (r >= (u32)k && r2 < (u32)k) {
            s_sel[0] = (u32)tid;
            s_sel[1] = (u32)k - r2;
        }
        __syncthreads();
        const u32 b1 = s_sel[0], remk = s_sel[1];
        float sg = ((u32)tid > b1 && c > 0u) ? (float)c * binval_of((u32)tid) : 0.f;
        #pragma unroll
        for (int off = 32; off > 0; off >>= 1) sg += __shfl_xor(sg, off);
        if (lane == 0) s_sg[wave] = sg;
        __syncthreads();
        if (tid == 0) {
            float t = 0.f;
            for (int w = 0; w < 16; ++w) t += s_sg[w];
            sum_sel = t + (float)remk * binval_of(b1);
        }
    }

    if (tid == 0) {
        float row_lb = 0.f, row_pb = 0.f;
        for (int w = 0; w < 16; ++w) { row_lb += s_rf[w]; row_pb += s_rf2[w]; }
        float nm  = (pcnt > 0) ? 1.f : 0.f;
        float pcn = fmaxf((float)pcnt, FLT_EPS_);
        g_rowc[b]          = row_lb * nm / pcn;
        g_rowc[B_ + b]     = (row_pb + sum_sel) * nm / pcn;
        g_rowc[2 * B_ + b] = nm / pcn;
    }
}

// ---------- Kernel C: B=128 mean (1 block, plain loads, deterministic) ----------
__global__ __launch_bounds__(128) void final_kernel(
    const float* __restrict__ g_rowc,
    float* __restrict__ out)
{
    const int tid  = threadIdx.x;
    const int lane = tid & 63;
    const int wave = tid >> 6;

    float lb_t = g_rowc[tid];
    float ll_t = g_rowc[B_ + tid];
    float w_t  = g_rowc[2 * B_ + tid];

    #pragma unroll
    for (int off = 32; off > 0; off >>= 1) {
        lb_t += __shfl_down(lb_t, off);
        ll_t += __shfl_down(ll_t, off);
        w_t  += __shfl_down(w_t, off);
    }
    __shared__ float sh[3][2];
    if (lane == 0) { sh[0][wave] = lb_t; sh[1][wave] = ll_t; sh[2][wave] = w_t; }
    __syncthreads();
    if (tid == 0) {
        float LB = (sh[0][0] + sh[0][1]) * (1.f / B_);
        float LL = (sh[1][0] + sh[1][1]) * (1.f / B_);
        float W  = (sh[2][0] + sh[2][1]) * (1.f / B_);
        out[0] = (LB + LL) * W;
        out[1] = LB;
        out[2] = LL;
    }
}

extern "C" void kernel_launch(void* const* d_in, const int* in_sizes, int n_in,
                              void* d_out, int out_size, void* d_ws, size_t ws_size,
                              hipStream_t stream) {
    const float* pbboxs  = (const float*)d_in[0];
    const float* plabels = (const float*)d_in[1];
    const float* gbboxs  = (const float*)d_in[2];
    const float* glabels = (const float*)d_in[3];
    const float* ancs    = (const float*)d_in[4];
    float* out    = (float*)d_out;
    float* g_rowc = (float*)d_ws;   // 384 floats, fully overwritten each call

    // MEASUREMENT ROUND 3: row_kernel launched TWICE (idempotent: all LDS
    // state re-initialized in-kernel, g_rowc rewritten with identical values).
    // dur_us - 15.2 = row_kernel WARM (L3-resident) exec time; separates
    // cold-HBM floor (harness evicts L3 every replay) from kernel-body cost.
    row_kernel<<<B_, NTHR, 0, stream>>>(
        pbboxs, plabels, gbboxs, glabels, ancs, g_rowc);
    row_kernel<<<B_, NTHR, 0, stream>>>(
        pbboxs, plabels, gbboxs, glabels, ancs, g_rowc);
    final_kernel<<<1, 128, 0, stream>>>(g_rowc, out);
}

// Round 22
// 15.097 us; speedup vs baseline: 1.5992x; 1.5992x over previous
//
#include <hip/hip_runtime.h>
#include <math.h>

#define B_ 128
#define N_ 16800
#define N4_ 4200             // uint4 units per row
#define NTAIL (N4_ - 4096)   // 104 tail uint4 units
#define NTHR 1024
#define NBINS 1024           // linear bins over x in [-8,8), width 1/64
#define HPAD32 1032          // padded sub-hist stride (u32)
#define NSUB 4
#define XSCALE 64.0f
#define XOFF 512.0f
#define INV_XSCALE (1.0f / 64.0f)
#define FLT_EPS_ 1.1920929e-7f

typedef unsigned int u32;

// numerically stable softplus: log(1+e^t) = max(t,0) + log1p(e^{-|t|})
__device__ __forceinline__ float softplus_of(float t) {
    return fmaxf(t, 0.f) + __logf(1.f + __expf(-fabsf(t)));
}
// x-space bin: monotone in x, hence monotone in lneg = softplus(x)
__device__ __forceinline__ u32 xbin_of(float x) {
    float fb = fmaf(x, XSCALE, XOFF);
    int ib = (int)fb;
    ib = (ib < 0) ? 0 : ((ib > NBINS - 1) ? NBINS - 1 : ib);
    return (u32)ib;
}
// value of a bin = softplus at its x-center
__device__ __forceinline__ float binval_of(u32 bin) {
    float cx = ((float)bin + 0.5f) * INV_XSCALE - 8.0f;
    return softplus_of(cx);
}

// One block per row (R20 structure + final micro-cuts):
//  - vectorized uint4 LDS-hist zeroing (was 4 serial scalar-store rounds)
//  - one barrier removed (reduce-publish covered by select's s_wt barrier)
__global__ __launch_bounds__(NTHR) void row_kernel(
    const float* __restrict__ pbboxs,
    const float* __restrict__ plabels,
    const float* __restrict__ gbboxs,
    const float* __restrict__ glabels,
    const float* __restrict__ ancs,
    float* __restrict__ g_rowc)   // [3][B_]
{
    __shared__ __align__(16) u32 s_hc[NSUB * HPAD32];   // 16.5 KB
    __shared__ int   s_posn[N_];            // 67.2 KB
    __shared__ float s_posv[N_];            // 67.2 KB
    __shared__ u32   s_pcnt;
    __shared__ float s_rf[16], s_rf2[16];
    __shared__ float s_sg[16];
    __shared__ u32   s_wt[16];
    __shared__ u32   s_sel[2];

    const int tid  = threadIdx.x;
    const int lane = tid & 63;
    const int wave = tid >> 6;
    const int b    = blockIdx.x;

    // vectorized hist init: 4128 u32 = 1032 uint4 (1024 + 8 tail)
    {
        uint4 z; z.x = 0u; z.y = 0u; z.z = 0u; z.w = 0u;
        ((uint4*)s_hc)[tid] = z;
        if (tid < 8) ((uint4*)s_hc)[1024 + tid] = z;
    }
    if (tid == 0) s_pcnt = 0u;
    __syncthreads();

    const uint4* pl4 = (const uint4*)(plabels + (size_t)b * N_);
    const uint4* gl4 = (const uint4*)(glabels + (size_t)b * N_);

    u32* myh = s_hc + (wave & (NSUB - 1)) * HPAD32;

    // ---- dense phase: ALL loads issued in one burst; no transcendentals ----
    {
        const bool has_tail = (tid < NTAIL);
        uint4 xu[4], yu[4], xt, yt;
        #pragma unroll
        for (int k = 0; k < 4; ++k) {
            xu[k] = pl4[tid + 1024 * k];
            yu[k] = gl4[tid + 1024 * k];
        }
        if (has_tail) { xt = pl4[4096 + tid]; yt = gl4[4096 + tid]; }

        #pragma unroll
        for (int k = 0; k < 4; ++k) {
            u32 xb[4] = {xu[k].x, xu[k].y, xu[k].z, xu[k].w};
            u32 yb[4] = {yu[k].x, yu[k].y, yu[k].z, yu[k].w};
            #pragma unroll
            for (int j = 0; j < 4; ++j) {
                float x = __uint_as_float(xb[j]);
                float y = __uint_as_float(yb[j]);
                bool pos = (y > 0.f);
                u32 bin = pos ? 0u : xbin_of(x);
                atomicAdd(&myh[bin], 1u);
                if (pos) {
                    u32 idx = atomicAdd(&s_pcnt, 1u);
                    s_posn[idx] = (tid + 1024 * k) * 4 + j;
                    s_posv[idx] = x;
                }
            }
        }
        if (has_tail) {
            u32 xb[4] = {xt.x, xt.y, xt.z, xt.w};
            u32 yb[4] = {yt.x, yt.y, yt.z, yt.w};
            #pragma unroll
            for (int j = 0; j < 4; ++j) {
                float x = __uint_as_float(xb[j]);
                float y = __uint_as_float(yb[j]);
                bool pos = (y > 0.f);
                u32 bin = pos ? 0u : xbin_of(x);
                atomicAdd(&myh[bin], 1u);
                if (pos) {
                    u32 idx = atomicAdd(&s_pcnt, 1u);
                    s_posn[idx] = (4096 + tid) * 4 + j;
                    s_posv[idx] = x;
                }
            }
        }
    }
    __syncthreads();

    // ---- positive phase: one scattered burst; bce = softplus(-x) ----
    const int pcnt = (int)s_pcnt;
    const float4* p4 = (const float4*)(pbboxs + (size_t)b * N_ * 4);
    const float4* g4 = (const float4*)(gbboxs + (size_t)b * N_ * 4);
    const float4* a4 = (const float4*)ancs;

    float acc_lb = 0.f, acc_pb = 0.f;
    for (int i = tid; i < pcnt; i += NTHR) {
        int n = s_posn[i];
        acc_pb += softplus_of(-s_posv[i]);
        float4 p = p4[n], g = g4[n], a = a4[n];
        float d0 = p.x - 10.f * __fdividef(g.x - a.x, a.z);
        float d1 = p.y - 10.f * __fdividef(g.y - a.y, a.w);
        float d2 = p.z - 5.f * __logf(__fdividef(g.z, a.z));
        float d3 = p.w - 5.f * __logf(__fdividef(g.w, a.w));
        float a0 = fabsf(d0), a1 = fabsf(d1), a2 = fabsf(d2), a3 = fabsf(d3);
        acc_lb += ((a0 < 1.f) ? 0.5f * d0 * d0 : a0 - 0.5f)
                + ((a1 < 1.f) ? 0.5f * d1 * d1 : a1 - 0.5f)
                + ((a2 < 1.f) ? 0.5f * d2 * d2 : a2 - 0.5f)
                + ((a3 < 1.f) ? 0.5f * d3 * d3 : a3 - 0.5f);
    }
    #pragma unroll
    for (int off = 32; off > 0; off >>= 1) {
        acc_lb += __shfl_xor(acc_lb, off);
        acc_pb += __shfl_xor(acc_pb, off);
    }
    if (lane == 0) { s_rf[wave] = acc_lb; s_rf2[wave] = acc_pb; }
    // no barrier here: select's s_wt barrier publishes s_rf/s_rf2 (k>0 path);
    // explicit barrier in the k==0 path below. Branch is block-uniform.

    // ---- in-block select: 1024 bins, one per thread ----
    const int k = (3 * pcnt > N_) ? N_ : 3 * pcnt;
    float sum_sel = 0.f;
    if (k > 0) {
        u32 c = s_hc[tid] + s_hc[HPAD32 + tid] + s_hc[2 * HPAD32 + tid] + s_hc[3 * HPAD32 + tid];
        u32 suf = c;
        #pragma unroll
        for (int off = 1; off < 64; off <<= 1) {
            u32 o = __shfl_down(suf, off);
            if (lane + off < 64) suf += o;
        }
        if (lane == 0) s_wt[wave] = suf;
        __syncthreads();                      // publishes s_wt AND s_rf/s_rf2
        u32 above = 0u;
        for (int w = wave + 1; w < 16; ++w) above += s_wt[w];
        u32 r  = suf + above;
        u32 r2 = r - c;
        if (r >= (u32)k && r2 < (u32)k) {     // exactly one bin fires; c >= 1
            s_sel[0] = (u32)tid;
            s_sel[1] = (u32)k - r2;
        }
        __syncthreads();
        const u32 b1 = s_sel[0], remk = s_sel[1];
        float sg = ((u32)tid > b1 && c > 0u) ? (float)c * binval_of((u32)tid) : 0.f;
        #pragma unroll
        for (int off = 32; off > 0; off >>= 1) sg += __shfl_xor(sg, off);
        if (lane == 0) s_sg[wave] = sg;
        __syncthreads();
        if (tid == 0) {
            float t = 0.f;
            for (int w = 0; w < 16; ++w) t += s_sg[w];
            sum_sel = t + (float)remk * binval_of(b1);
        }
    } else {
        __syncthreads();                      // publish s_rf/s_rf2 for tid 0
    }

    if (tid == 0) {
        float row_lb = 0.f, row_pb = 0.f;
        for (int w = 0; w < 16; ++w) { row_lb += s_rf[w]; row_pb += s_rf2[w]; }
        float nm  = (pcnt > 0) ? 1.f : 0.f;
        float pcn = fmaxf((float)pcnt, FLT_EPS_);
        g_rowc[b]          = row_lb * nm / pcn;
        g_rowc[B_ + b]     = (row_pb + sum_sel) * nm / pcn;
        g_rowc[2 * B_ + b] = nm / pcn;
    }
}

// ---------- Kernel C: B=128 mean (1 block, plain loads, deterministic) ----------
__global__ __launch_bounds__(128) void final_kernel(
    const float* __restrict__ g_rowc,
    float* __restrict__ out)
{
    const int tid  = threadIdx.x;
    const int lane = tid & 63;
    const int wave = tid >> 6;

    float lb_t = g_rowc[tid];
    float ll_t = g_rowc[B_ + tid];
    float w_t  = g_rowc[2 * B_ + tid];

    #pragma unroll
    for (int off = 32; off > 0; off >>= 1) {
        lb_t += __shfl_down(lb_t, off);
        ll_t += __shfl_down(ll_t, off);
        w_t  += __shfl_down(w_t, off);
    }
    __shared__ float sh[3][2];
    if (lane == 0) { sh[0][wave] = lb_t; sh[1][wave] = ll_t; sh[2][wave] = w_t; }
    __syncthreads();
    if (tid == 0) {
        float LB = (sh[0][0] + sh[0][1]) * (1.f / B_);
        float LL = (sh[1][0] + sh[1][1]) * (1.f / B_);
        float W  = (sh[2][0] + sh[2][1]) * (1.f / B_);
        out[0] = (LB + LL) * W;
        out[1] = LB;
        out[2] = LL;
    }
}

extern "C" void kernel_launch(void* const* d_in, const int* in_sizes, int n_in,
                              void* d_out, int out_size, void* d_ws, size_t ws_size,
                              hipStream_t stream) {
    const float* pbboxs  = (const float*)d_in[0];
    const float* plabels = (const float*)d_in[1];
    const float* gbboxs  = (const float*)d_in[2];
    const float* glabels = (const float*)d_in[3];
    const float* ancs    = (const float*)d_in[4];
    float* out    = (float*)d_out;
    float* g_rowc = (float*)d_ws;   // 384 floats, fully overwritten each call

    row_kernel<<<B_, NTHR, 0, stream>>>(
        pbboxs, plabels, gbboxs, glabels, ancs, g_rowc);
    final_kernel<<<1, 128, 0, stream>>>(g_rowc, out);
}